// Round 11
// baseline (161.925 us; speedup 1.0000x reference)
//
#include <hip/hip_runtime.h>
#include <stdint.h>

#define EPS 1e-5f
#define NG 64
#define NP 8      // dst-range partitions (== XCD count; partition p = blockIdx & 7)
#define MSLOT 64  // padded CSR slot per node (deg ~ Poisson(16); P(>64) ~ 1e-20)

typedef float f32x4 __attribute__((ext_vector_type(4)));
typedef __bf16 bf16x8 __attribute__((ext_vector_type(8)));
typedef unsigned short u16x8 __attribute__((ext_vector_type(8)));

__device__ __forceinline__ unsigned short f2bf(float f) {
    union { float f; uint32_t u; } v; v.f = f;
    uint32_t r = v.u + 0x7fff + ((v.u >> 16) & 1);  // round-to-nearest-even
    return (unsigned short)(r >> 16);
}
__device__ __forceinline__ float bflo(uint32_t u) {
    union { uint32_t u; float f; } v; v.u = u << 16; return v.f;
}
__device__ __forceinline__ float bfhi(uint32_t u) {
    union { uint32_t u; float f; } v; v.u = u & 0xffff0000u; return v.f;
}

// ---------------- setup: rowpos[i] = i*64, zero accumulators, build W fragments ----------------
__global__ __launch_bounds__(256) void setup(const float* __restrict__ W,
                                             unsigned short* __restrict__ wf,
                                             int* __restrict__ rowpos, int N,
                                             int* __restrict__ zbase, int zcount) {
    int i = blockIdx.x * 256 + threadIdx.x;
    if (i < N) rowpos[i] = i << 6;
    if (i < zcount) zbase[i] = 0;
    if (blockIdx.x == 0) {
        for (int k = threadIdx.x; k < 512; k += 256) {
            int lane = k & 63;
            int c = k >> 7;
            int s = (k >> 6) & 1;
            int col = 16 * c + (lane & 15);
            int k0 = 32 * s + (lane >> 4) * 8;
#pragma unroll
            for (int j = 0; j < 8; ++j)
                wf[k * 8 + j] = f2bf(W[(k0 + j) * 64 + col]);
        }
    }
}

// ---------------- fill: dst-range partitioned -> ALL atomics & stores XCD-local ----------------
__global__ __launch_bounds__(256) void fill_xcd(const int* __restrict__ src,
                                                const int* __restrict__ dst,
                                                int* __restrict__ rowpos,
                                                unsigned short* __restrict__ csr2,
                                                int E, int N, int rng, int chunk) {
    int b = blockIdx.x;
    int p = b & (NP - 1);
    int lo = p * rng;
    int hi = min(lo + rng, N);
    int base = (b >> 3) * chunk;
    int end = min(base + chunk, E);
    for (int e = base + threadIdx.x; e < end; e += 256) {
        int d = dst[e];
        if (d >= lo && d < hi) {
            int pos = atomicAdd(&rowpos[d], 1);
            if (pos < (d << 6) + MSLOT)  // overflow guard (statistically never)
                __builtin_nontemporal_store((unsigned short)src[e], &csr2[pos]);
        }
    }
}

// ---------------- prep: true degree from cursor, dinv, clamped ndeg ----------------
__global__ void prep(const int* __restrict__ rowpos, float* __restrict__ dinv,
                     unsigned short* __restrict__ ndeg, int N) {
    int i = blockIdx.x * 256 + threadIdx.x;
    if (i >= N) return;
    int deg = rowpos[i] - (i << 6);
    ndeg[i] = (unsigned short)min(deg, MSLOT);
    dinv[i] = rsqrtf(1.0f + (float)deg);
}

// ---------------- h' = dinv * (x @ W) via MFMA, stored bf16 ----------------
__global__ __launch_bounds__(256) void gemm_mfma(const float* __restrict__ x,
                                                 const unsigned short* __restrict__ wf,
                                                 const float* __restrict__ dinv,
                                                 unsigned short* __restrict__ hb, int N) {
    int w = threadIdx.x >> 6;
    int lane = threadIdx.x & 63;
    int rowbase = blockIdx.x * 64 + w * 16;

    bf16x8 bfrag[4][2];
#pragma unroll
    for (int c = 0; c < 4; ++c)
#pragma unroll
        for (int s = 0; s < 2; ++s) {
            u16x8 u = *reinterpret_cast<const u16x8*>(wf + ((c * 2 + s) * 64 + lane) * 8);
            bfrag[c][s] = __builtin_bit_cast(bf16x8, u);
        }

    int ar = rowbase + (lane & 15);
    int k0 = (lane >> 4) * 8;
    bf16x8 afrag[2];
#pragma unroll
    for (int s = 0; s < 2; ++s) {
        u16x8 u = {0, 0, 0, 0, 0, 0, 0, 0};
        if (ar < N) {
            const float* xp = x + (size_t)ar * 64 + 32 * s + k0;
#pragma unroll
            for (int j = 0; j < 8; ++j) u[j] = f2bf(xp[j]);
        }
        afrag[s] = __builtin_bit_cast(bf16x8, u);
    }

    f32x4 acc[4];
#pragma unroll
    for (int c = 0; c < 4; ++c) acc[c] = (f32x4){0.f, 0.f, 0.f, 0.f};
#pragma unroll
    for (int s = 0; s < 2; ++s)
#pragma unroll
        for (int c = 0; c < 4; ++c)
            acc[c] = __builtin_amdgcn_mfma_f32_16x16x32_bf16(afrag[s], bfrag[c][s], acc[c], 0, 0, 0);

    int r0 = rowbase + (lane >> 4) * 4;
    int col = lane & 15;
#pragma unroll
    for (int j = 0; j < 4; ++j) {
        int node = r0 + j;
        if (node < N) {
            float dd = dinv[node];
#pragma unroll
            for (int c = 0; c < 4; ++c)
                hb[(size_t)node * 64 + 16 * c + col] = f2bf(acc[c][j] * dd);
        }
    }
}

// ---------------- gather conv + fused per-graph stats ----------------
// ONE node per wave: 4 neighbor groups (g=lane>>4) x 16 col lanes (c=lane&15, 8B each).
// No degree divergence; indices preloaded per-lane; unroll-by-2 -> 8 row loads in flight.
__global__ __launch_bounds__(256) void gather_stats(const unsigned short* __restrict__ ndeg,
                                                    const unsigned short* __restrict__ csr2,
                                                    const float* __restrict__ dinv,
                                                    const uint2* __restrict__ hb2,
                                                    const float* __restrict__ bia,
                                                    const int* __restrict__ batch,
                                                    float* __restrict__ out,
                                                    float* __restrict__ macc,
                                                    float* __restrict__ vacc,
                                                    int* __restrict__ cntacc, int N) {
    int wv = threadIdx.x >> 6;       // wave 0..3
    int nd = blockIdx.x * 4 + wv;    // one node per wave
    int lane = threadIdx.x & 63;
    int g = lane >> 4;               // neighbor group 0..3
    int c = lane & 15;               // col quad (cols 4c..4c+3)
    bool valid = nd < N;

    __shared__ int bsh[4];
    __shared__ float sm[64], sv[64];
    if (threadIdx.x < 4)
        bsh[threadIdx.x] = (blockIdx.x * 4 + (int)threadIdx.x < N) ? batch[blockIdx.x * 4 + threadIdx.x] : -1;

    int deg = 0, myidx = 0, s0 = nd << 6;
    if (valid) {
        deg = ndeg[nd];
        myidx = csr2[s0 + lane];     // all 64 slot indices, one per lane (coalesced 128B)
    }
    float a0 = 0.f, a1 = 0.f, a2 = 0.f, a3 = 0.f;
    int iters = (deg + 3) >> 2;
    int it = 0;
    for (; it + 2 <= iters; it += 2) {
        int sA = it * 4 + g, sB = sA + 4;
        int iA = __shfl(myidx, sA), iB = __shfl(myidx, sB);
        uint2 vA = {0u, 0u}, vB = {0u, 0u};
        if (sA < deg) vA = hb2[(size_t)iA * 16 + c];
        if (sB < deg) vB = hb2[(size_t)iB * 16 + c];
        a0 += bflo(vA.x) + bflo(vB.x);
        a1 += bfhi(vA.x) + bfhi(vB.x);
        a2 += bflo(vA.y) + bflo(vB.y);
        a3 += bfhi(vA.y) + bfhi(vB.y);
    }
    if (it < iters) {
        int sA = it * 4 + g;
        int iA = __shfl(myidx, sA);
        uint2 vA = {0u, 0u};
        if (sA < deg) vA = hb2[(size_t)iA * 16 + c];
        a0 += bflo(vA.x);
        a1 += bfhi(vA.x);
        a2 += bflo(vA.y);
        a3 += bfhi(vA.y);
    }
    // reduce across the 4 neighbor groups (lanes ^16, ^32)
    a0 += __shfl_xor(a0, 16); a0 += __shfl_xor(a0, 32);
    a1 += __shfl_xor(a1, 16); a1 += __shfl_xor(a1, 32);
    a2 += __shfl_xor(a2, 16); a2 += __shfl_xor(a2, 32);
    a3 += __shfl_xor(a3, 16); a3 += __shfl_xor(a3, 32);

    float r0 = 0.f, r1 = 0.f, r2 = 0.f, r3 = 0.f;
    if (valid && lane < 16) {
        uint2 hv = hb2[(size_t)nd * 16 + c];   // self loop (prescaled)
        a0 += bflo(hv.x); a1 += bfhi(hv.x);
        a2 += bflo(hv.y); a3 += bfhi(hv.y);
        float dd = dinv[nd];
        float4 bb = *reinterpret_cast<const float4*>(bia + 4 * c);
        r0 = bb.x + dd * a0; r1 = bb.y + dd * a1;
        r2 = bb.z + dd * a2; r3 = bb.w + dd * a3;
        *reinterpret_cast<float4*>(out + (size_t)nd * 64 + 4 * c) = make_float4(r0, r1, r2, r3);
    }
    __syncthreads();

    int s = 0;
    while (s < 4) {
        int gg = bsh[s];
        if (gg < 0) break;
        int e = s + 1;
        while (e < 4 && bsh[e] == gg) ++e;
        if (threadIdx.x < 64) { sm[threadIdx.x] = 0.f; sv[threadIdx.x] = 0.f; }
        __syncthreads();
        if (valid && lane < 16 && wv >= s && wv < e) {
            atomicAdd(&sm[4 * c + 0], r0); atomicAdd(&sv[4 * c + 0], r0 * r0);
            atomicAdd(&sm[4 * c + 1], r1); atomicAdd(&sv[4 * c + 1], r1 * r1);
            atomicAdd(&sm[4 * c + 2], r2); atomicAdd(&sv[4 * c + 2], r2 * r2);
            atomicAdd(&sm[4 * c + 3], r3); atomicAdd(&sv[4 * c + 3], r3 * r3);
        }
        __syncthreads();
        if (threadIdx.x < 64) {
            atomicAdd(&macc[gg * 64 + threadIdx.x], sm[threadIdx.x]);
            atomicAdd(&vacc[gg * 64 + threadIdx.x], sv[threadIdx.x]);
        }
        if (threadIdx.x == 0) atomicAdd(&cntacc[gg], e - s);
        __syncthreads();
        s = e;
    }
}

// ---------------- final: finalize + normalize + affine + relu, float4 ----------------
__global__ void gn_final(float* __restrict__ out, const int* __restrict__ batch,
                         const float* __restrict__ ms, const float* __restrict__ macc,
                         const float* __restrict__ vacc, const int* __restrict__ cntacc,
                         const float* __restrict__ gw, const float* __restrict__ gb,
                         int total4) {
    int idx = blockIdx.x * 256 + threadIdx.x;
    if (idx >= total4) return;
    int i = idx >> 4, q = idx & 15;
    int g = batch[i];
    float inv = 1.f / (float)max(cntacc[g], 1);
    float4 mv = *reinterpret_cast<const float4*>(macc + g * 64 + 4 * q);
    float4 vv = *reinterpret_cast<const float4*>(vacc + g * 64 + 4 * q);
    float4 msf = *reinterpret_cast<const float4*>(ms + 4 * q);
    float4 gwv = *reinterpret_cast<const float4*>(gw + 4 * q);
    float4 gbv = *reinterpret_cast<const float4*>(gb + 4 * q);
    float4 o = *reinterpret_cast<const float4*>(out + (size_t)i * 64 + 4 * q);
    float m, var, y;
    float4 res;
    m = mv.x * inv; var = vv.x * inv - m * m * msf.x * (2.f - msf.x);
    y = (o.x - msf.x * m) * rsqrtf(var + EPS); res.x = fmaxf(gwv.x * y + gbv.x, 0.f);
    m = mv.y * inv; var = vv.y * inv - m * m * msf.y * (2.f - msf.y);
    y = (o.y - msf.y * m) * rsqrtf(var + EPS); res.y = fmaxf(gwv.y * y + gbv.y, 0.f);
    m = mv.z * inv; var = vv.z * inv - m * m * msf.z * (2.f - msf.z);
    y = (o.z - msf.z * m) * rsqrtf(var + EPS); res.z = fmaxf(gwv.z * y + gbv.z, 0.f);
    m = mv.w * inv; var = vv.w * inv - m * m * msf.w * (2.f - msf.w);
    y = (o.w - msf.w * m) * rsqrtf(var + EPS); res.w = fmaxf(gwv.w * y + gbv.w, 0.f);
    *reinterpret_cast<float4*>(out + (size_t)i * 64 + 4 * q) = res;
}

extern "C" void kernel_launch(void* const* d_in, const int* in_sizes, int n_in,
                              void* d_out, int out_size, void* d_ws, size_t ws_size,
                              hipStream_t stream) {
    const float* x  = (const float*)d_in[0];
    const float* W  = (const float*)d_in[1];
    const float* b  = (const float*)d_in[2];
    const float* gw = (const float*)d_in[3];
    const float* gb = (const float*)d_in[4];
    const float* ms = (const float*)d_in[5];
    const int*   edge  = (const int*)d_in[6];
    const int*   batch = (const int*)d_in[7];

    int N = in_sizes[0] / 64;
    int E = in_sizes[6] / 2;
    const int* src = edge;
    const int* dst = edge + E;

    float* out = (float*)d_out;

    // workspace layout (contiguous zero region: macc | vacc | cntacc)
    unsigned short* hb = (unsigned short*)d_ws;          // N*64 bf16 (prescaled)
    float* dinv      = (float*)(hb + (size_t)N * 64);    // N f32
    int*   rowpos    = (int*)(dinv + N);                 // N int (write cursors)
    float* macc      = (float*)(rowpos + N);             // 64*64
    float* vacc      = macc + 64 * 64;                   // 64*64
    int*   cntacc    = (int*)(vacc + 64 * 64);           // 64 (+pad)
    unsigned short* ndeg = (unsigned short*)(cntacc + 80);  // N ushort
    unsigned short* csr2 = ndeg + N + 32;                // N*64 ushort (padded slots)
    unsigned short* wf   = csr2 + (size_t)N * MSLOT;     // 4096 bf16 W-fragments

    int nblocks = (N + 255) / 256;
    int chunk = (E + 255) / 256;              // per-block edge chunk (256 blocks/partition)
    int rng = (N + NP - 1) / NP;              // nodes per partition
    int zcount = 2 * 64 * 64 + 80;            // macc + vacc + cntacc(+pad)
    int setup_n = max(N, zcount);

    setup<<<(setup_n + 255) / 256, 256, 0, stream>>>(W, wf, rowpos, N, (int*)macc, zcount);
    fill_xcd<<<2048, 256, 0, stream>>>(src, dst, rowpos, csr2, E, N, rng, chunk);
    prep<<<nblocks, 256, 0, stream>>>(rowpos, dinv, ndeg, N);
    gemm_mfma<<<(N + 63) / 64, 256, 0, stream>>>(x, wf, dinv, hb, N);
    gather_stats<<<(N + 3) / 4, 256, 0, stream>>>(ndeg, csr2, dinv, (const uint2*)hb, b,
                                                  batch, out, macc, vacc, cntacc, N);
    gn_final<<<(N * 16 + 255) / 256, 256, 0, stream>>>(out, batch, ms, macc, vacc, cntacc,
                                                       gw, gb, N * 16);
}

// Round 12
// 106.437 us; speedup vs baseline: 1.5213x; 1.5213x over previous
//
#include <hip/hip_runtime.h>
#include <stdint.h>

#define EPS 1e-5f
#define NG 64
#define NP 8      // dst-range partitions (== XCD count; partition p = blockIdx & 7)
#define MSLOT 64  // padded CSR slot per node (deg ~ Poisson(16); P(>64) ~ 1e-20)
#define CH 128    // rows per stats chunk

typedef float f32x4 __attribute__((ext_vector_type(4)));
typedef __bf16 bf16x8 __attribute__((ext_vector_type(8)));
typedef unsigned short u16x8 __attribute__((ext_vector_type(8)));

__device__ __forceinline__ unsigned short f2bf(float f) {
    union { float f; uint32_t u; } v; v.f = f;
    uint32_t r = v.u + 0x7fff + ((v.u >> 16) & 1);  // round-to-nearest-even
    return (unsigned short)(r >> 16);
}
__device__ __forceinline__ float bflo(uint32_t u) {
    union { uint32_t u; float f; } v; v.u = u << 16; return v.f;
}
__device__ __forceinline__ float bfhi(uint32_t u) {
    union { uint32_t u; float f; } v; v.u = u & 0xffff0000u; return v.f;
}

// ---------------- setup: rowpos[i] = i*64, zero accumulators, build W fragments ----------------
__global__ __launch_bounds__(256) void setup(const float* __restrict__ W,
                                             unsigned short* __restrict__ wf,
                                             int* __restrict__ rowpos, int N,
                                             int* __restrict__ zbase, int zcount) {
    int i = blockIdx.x * 256 + threadIdx.x;
    if (i < N) rowpos[i] = i << 6;
    if (i < zcount) zbase[i] = 0;
    if (blockIdx.x == 0) {
        for (int k = threadIdx.x; k < 512; k += 256) {
            int lane = k & 63;
            int c = k >> 7;
            int s = (k >> 6) & 1;
            int col = 16 * c + (lane & 15);
            int k0 = 32 * s + (lane >> 4) * 8;
#pragma unroll
            for (int j = 0; j < 8; ++j)
                wf[k * 8 + j] = f2bf(W[(k0 + j) * 64 + col]);
        }
    }
}

// ---------------- fill: dst-range partitioned -> ALL atomics & stores XCD-local ----------------
__global__ __launch_bounds__(256) void fill_xcd(const int* __restrict__ src,
                                                const int* __restrict__ dst,
                                                int* __restrict__ rowpos,
                                                unsigned short* __restrict__ csr2,
                                                int E, int N, int rng, int chunk) {
    int b = blockIdx.x;
    int p = b & (NP - 1);
    int lo = p * rng;
    int hi = min(lo + rng, N);
    int base = (b >> 3) * chunk;
    int end = min(base + chunk, E);
    for (int e = base + threadIdx.x; e < end; e += 256) {
        int d = dst[e];
        if (d >= lo && d < hi) {
            int pos = atomicAdd(&rowpos[d], 1);
            if (pos < (d << 6) + MSLOT)  // overflow guard (statistically never)
                __builtin_nontemporal_store((unsigned short)src[e], &csr2[pos]);
        }
    }
}

// ---------------- prep: true degree from cursor, dinv, clamped ndeg ----------------
__global__ void prep(const int* __restrict__ rowpos, float* __restrict__ dinv,
                     unsigned short* __restrict__ ndeg, int N) {
    int i = blockIdx.x * 256 + threadIdx.x;
    if (i >= N) return;
    int deg = rowpos[i] - (i << 6);
    ndeg[i] = (unsigned short)min(deg, MSLOT);
    dinv[i] = rsqrtf(1.0f + (float)deg);
}

// ---------------- h' = dinv * (x @ W) via MFMA, stored bf16 ----------------
__global__ __launch_bounds__(256) void gemm_mfma(const float* __restrict__ x,
                                                 const unsigned short* __restrict__ wf,
                                                 const float* __restrict__ dinv,
                                                 unsigned short* __restrict__ hb, int N) {
    int w = threadIdx.x >> 6;
    int lane = threadIdx.x & 63;
    int rowbase = blockIdx.x * 64 + w * 16;

    bf16x8 bfrag[4][2];
#pragma unroll
    for (int c = 0; c < 4; ++c)
#pragma unroll
        for (int s = 0; s < 2; ++s) {
            u16x8 u = *reinterpret_cast<const u16x8*>(wf + ((c * 2 + s) * 64 + lane) * 8);
            bfrag[c][s] = __builtin_bit_cast(bf16x8, u);
        }

    int ar = rowbase + (lane & 15);
    int k0 = (lane >> 4) * 8;
    bf16x8 afrag[2];
#pragma unroll
    for (int s = 0; s < 2; ++s) {
        u16x8 u = {0, 0, 0, 0, 0, 0, 0, 0};
        if (ar < N) {
            const float* xp = x + (size_t)ar * 64 + 32 * s + k0;
#pragma unroll
            for (int j = 0; j < 8; ++j) u[j] = f2bf(xp[j]);
        }
        afrag[s] = __builtin_bit_cast(bf16x8, u);
    }

    f32x4 acc[4];
#pragma unroll
    for (int c = 0; c < 4; ++c) acc[c] = (f32x4){0.f, 0.f, 0.f, 0.f};
#pragma unroll
    for (int s = 0; s < 2; ++s)
#pragma unroll
        for (int c = 0; c < 4; ++c)
            acc[c] = __builtin_amdgcn_mfma_f32_16x16x32_bf16(afrag[s], bfrag[c][s], acc[c], 0, 0, 0);

    int r0 = rowbase + (lane >> 4) * 4;
    int col = lane & 15;
#pragma unroll
    for (int j = 0; j < 4; ++j) {
        int node = r0 + j;
        if (node < N) {
            float dd = dinv[node];
#pragma unroll
            for (int c = 0; c < 4; ++c)
                hb[(size_t)node * 64 + 16 * c + col] = f2bf(acc[c][j] * dd);
        }
    }
}

// ---------------- gather conv: 4 nodes/wave, 16 lanes x uint2; pure (no stats) ----------------
__global__ __launch_bounds__(256) void gather_conv(const unsigned short* __restrict__ ndeg,
                                                   const unsigned short* __restrict__ csr2,
                                                   const float* __restrict__ dinv,
                                                   const uint2* __restrict__ hb2,
                                                   const float* __restrict__ bia,
                                                   float* __restrict__ out, int N) {
    int nd = blockIdx.x * 16 + (threadIdx.x >> 4);
    if (nd >= N) return;
    int l = threadIdx.x & 15;  // covers cols 4l..4l+3 (8 B)
    float dd = dinv[nd];
    uint2 hv = hb2[(size_t)nd * 16 + l];  // self loop (prescaled)
    float a0 = bflo(hv.x), a1 = bfhi(hv.x), a2 = bflo(hv.y), a3 = bfhi(hv.y);
    int s0 = nd << 6;
    int s1 = s0 + ndeg[nd];
    int j = s0;
    for (; j + 4 <= s1; j += 4) {
        // 4 indices in one 8B load (slot base 128B-aligned, j stays 4-slot aligned)
        unsigned long long iq = *reinterpret_cast<const unsigned long long*>(csr2 + j);
        int i0 = (int)(iq & 0xffff), i1 = (int)((iq >> 16) & 0xffff);
        int i2 = (int)((iq >> 32) & 0xffff), i3 = (int)(iq >> 48);
        uint2 v0 = hb2[(size_t)i0 * 16 + l];
        uint2 v1 = hb2[(size_t)i1 * 16 + l];
        uint2 v2 = hb2[(size_t)i2 * 16 + l];
        uint2 v3 = hb2[(size_t)i3 * 16 + l];
        a0 += bflo(v0.x) + bflo(v1.x) + bflo(v2.x) + bflo(v3.x);
        a1 += bfhi(v0.x) + bfhi(v1.x) + bfhi(v2.x) + bfhi(v3.x);
        a2 += bflo(v0.y) + bflo(v1.y) + bflo(v2.y) + bflo(v3.y);
        a3 += bfhi(v0.y) + bfhi(v1.y) + bfhi(v2.y) + bfhi(v3.y);
    }
    for (; j < s1; ++j) {
        uint2 v = hb2[(size_t)csr2[j] * 16 + l];
        a0 += bflo(v.x);
        a1 += bfhi(v.x);
        a2 += bflo(v.y);
        a3 += bfhi(v.y);
    }
    float4 bb = *reinterpret_cast<const float4*>(bia + 4 * l);
    float4 r;
    r.x = bb.x + dd * a0;
    r.y = bb.y + dd * a1;
    r.z = bb.z + dd * a2;
    r.w = bb.w + dd * a3;
    *reinterpret_cast<float4*>(out + (size_t)nd * 64 + 4 * l) = r;
}

// ---------------- chunk-parallel per-graph sum / sumsq / count ----------------
__global__ __launch_bounds__(256) void stats_partial(const float* __restrict__ out,
                                                     const int* __restrict__ batch,
                                                     float* __restrict__ macc,
                                                     float* __restrict__ vacc,
                                                     int* __restrict__ cntacc, int N) {
    int c0 = blockIdx.x * CH;
    int c1 = min(c0 + CH, N);
    if (c0 >= N) return;
    int t = threadIdx.x, col = t & 63, rg = t >> 6;
    __shared__ int bsh[CH];
    __shared__ float red[4][64], red2[4][64];
    for (int i = t; i < c1 - c0; i += 256) bsh[i] = batch[c0 + i];
    __syncthreads();
    int s = c0;
    while (s < c1) {
        int g = bsh[s - c0];
        int e = s + 1;
        while (e < c1 && bsh[e - c0] == g) ++e;
        float sum = 0.f, sq = 0.f;
        for (int r = s + rg; r < e; r += 4) {
            float v = out[(size_t)r * 64 + col];
            sum += v;
            sq += v * v;
        }
        red[rg][col] = sum;
        red2[rg][col] = sq;
        __syncthreads();
        if (t < 64) {
            atomicAdd(&macc[g * 64 + t], red[0][t] + red[1][t] + red[2][t] + red[3][t]);
            atomicAdd(&vacc[g * 64 + t], red2[0][t] + red2[1][t] + red2[2][t] + red2[3][t]);
        }
        if (t == 0) atomicAdd(&cntacc[g], e - s);
        __syncthreads();
        s = e;
    }
}

// ---------------- final: finalize + normalize + affine + relu, float4 ----------------
__global__ void gn_final(float* __restrict__ out, const int* __restrict__ batch,
                         const float* __restrict__ ms, const float* __restrict__ macc,
                         const float* __restrict__ vacc, const int* __restrict__ cntacc,
                         const float* __restrict__ gw, const float* __restrict__ gb,
                         int total4) {
    int idx = blockIdx.x * 256 + threadIdx.x;
    if (idx >= total4) return;
    int i = idx >> 4, q = idx & 15;
    int g = batch[i];
    float inv = 1.f / (float)max(cntacc[g], 1);
    float4 mv = *reinterpret_cast<const float4*>(macc + g * 64 + 4 * q);
    float4 vv = *reinterpret_cast<const float4*>(vacc + g * 64 + 4 * q);
    float4 msf = *reinterpret_cast<const float4*>(ms + 4 * q);
    float4 gwv = *reinterpret_cast<const float4*>(gw + 4 * q);
    float4 gbv = *reinterpret_cast<const float4*>(gb + 4 * q);
    float4 o = *reinterpret_cast<const float4*>(out + (size_t)i * 64 + 4 * q);
    float m, var, y;
    float4 res;
    m = mv.x * inv; var = vv.x * inv - m * m * msf.x * (2.f - msf.x);
    y = (o.x - msf.x * m) * rsqrtf(var + EPS); res.x = fmaxf(gwv.x * y + gbv.x, 0.f);
    m = mv.y * inv; var = vv.y * inv - m * m * msf.y * (2.f - msf.y);
    y = (o.y - msf.y * m) * rsqrtf(var + EPS); res.y = fmaxf(gwv.y * y + gbv.y, 0.f);
    m = mv.z * inv; var = vv.z * inv - m * m * msf.z * (2.f - msf.z);
    y = (o.z - msf.z * m) * rsqrtf(var + EPS); res.z = fmaxf(gwv.z * y + gbv.z, 0.f);
    m = mv.w * inv; var = vv.w * inv - m * m * msf.w * (2.f - msf.w);
    y = (o.w - msf.w * m) * rsqrtf(var + EPS); res.w = fmaxf(gwv.w * y + gbv.w, 0.f);
    *reinterpret_cast<float4*>(out + (size_t)i * 64 + 4 * q) = res;
}

extern "C" void kernel_launch(void* const* d_in, const int* in_sizes, int n_in,
                              void* d_out, int out_size, void* d_ws, size_t ws_size,
                              hipStream_t stream) {
    const float* x  = (const float*)d_in[0];
    const float* W  = (const float*)d_in[1];
    const float* b  = (const float*)d_in[2];
    const float* gw = (const float*)d_in[3];
    const float* gb = (const float*)d_in[4];
    const float* ms = (const float*)d_in[5];
    const int*   edge  = (const int*)d_in[6];
    const int*   batch = (const int*)d_in[7];

    int N = in_sizes[0] / 64;
    int E = in_sizes[6] / 2;
    const int* src = edge;
    const int* dst = edge + E;

    float* out = (float*)d_out;

    // workspace layout (contiguous zero region: macc | vacc | cntacc)
    unsigned short* hb = (unsigned short*)d_ws;          // N*64 bf16 (prescaled)
    float* dinv      = (float*)(hb + (size_t)N * 64);    // N f32
    int*   rowpos    = (int*)(dinv + N);                 // N int (write cursors)
    float* macc      = (float*)(rowpos + N);             // 64*64
    float* vacc      = macc + 64 * 64;                   // 64*64
    int*   cntacc    = (int*)(vacc + 64 * 64);           // 64 (+pad)
    unsigned short* ndeg = (unsigned short*)(cntacc + 80);  // N ushort
    unsigned short* csr2 = ndeg + N + 32;                // N*64 ushort (padded slots)
    unsigned short* wf   = csr2 + (size_t)N * MSLOT;     // 4096 bf16 W-fragments

    int nblocks = (N + 255) / 256;
    int chunk = (E + 255) / 256;              // per-block edge chunk (256 blocks/partition)
    int rng = (N + NP - 1) / NP;              // nodes per partition
    int zcount = 2 * 64 * 64 + 80;            // macc + vacc + cntacc(+pad)
    int setup_n = max(N, zcount);

    setup<<<(setup_n + 255) / 256, 256, 0, stream>>>(W, wf, rowpos, N, (int*)macc, zcount);
    fill_xcd<<<2048, 256, 0, stream>>>(src, dst, rowpos, csr2, E, N, rng, chunk);
    prep<<<nblocks, 256, 0, stream>>>(rowpos, dinv, ndeg, N);
    gemm_mfma<<<(N + 63) / 64, 256, 0, stream>>>(x, wf, dinv, hb, N);
    gather_conv<<<(N + 15) / 16, 256, 0, stream>>>(ndeg, csr2, dinv, (const uint2*)hb, b, out, N);
    stats_partial<<<(N + CH - 1) / CH, 256, 0, stream>>>(out, batch, macc, vacc, cntacc, N);
    gn_final<<<(N * 16 + 255) / 256, 256, 0, stream>>>(out, batch, ms, macc, vacc, cntacc,
                                                       gw, gb, N * 16);
}

// Round 14
// 103.001 us; speedup vs baseline: 1.5721x; 1.0334x over previous
//
#include <hip/hip_runtime.h>
#include <stdint.h>

#define EPS 1e-5f
#define NG 64
#define NP 8      // dst-range partitions (== XCD count; partition p = blockIdx & 7)
#define MSLOT 64  // padded CSR slot per node (deg ~ Poisson(16); P(>64) ~ 1e-20)
#define CH 128    // rows per stats chunk

typedef float f32x4 __attribute__((ext_vector_type(4)));
typedef __bf16 bf16x8 __attribute__((ext_vector_type(8)));
typedef unsigned short u16x8 __attribute__((ext_vector_type(8)));

__device__ __forceinline__ unsigned short f2bf(float f) {
    union { float f; uint32_t u; } v; v.f = f;
    uint32_t r = v.u + 0x7fff + ((v.u >> 16) & 1);  // round-to-nearest-even
    return (unsigned short)(r >> 16);
}
__device__ __forceinline__ float bflo(uint32_t u) {
    union { uint32_t u; float f; } v; v.u = u << 16; return v.f;
}
__device__ __forceinline__ float bfhi(uint32_t u) {
    union { uint32_t u; float f; } v; v.u = u & 0xffff0000u; return v.f;
}

// ---------------- setup: rowpos[i] = i*64, zero accumulators, build W fragments ----------------
__global__ __launch_bounds__(256) void setup(const float* __restrict__ W,
                                             unsigned short* __restrict__ wf,
                                             int* __restrict__ rowpos, int N,
                                             int* __restrict__ zbase, int zcount) {
    int i = blockIdx.x * 256 + threadIdx.x;
    if (i < N) rowpos[i] = i << 6;
    if (i < zcount) zbase[i] = 0;
    if (blockIdx.x == 0) {
        for (int k = threadIdx.x; k < 512; k += 256) {
            int lane = k & 63;
            int c = k >> 7;
            int s = (k >> 6) & 1;
            int col = 16 * c + (lane & 15);
            int k0 = 32 * s + (lane >> 4) * 8;
#pragma unroll
            for (int j = 0; j < 8; ++j)
                wf[k * 8 + j] = f2bf(W[(k0 + j) * 64 + col]);
        }
    }
}

// ---------------- fill: dst-range partitioned -> ALL atomics & stores XCD-local ----------------
__global__ __launch_bounds__(256) void fill_xcd(const int* __restrict__ src,
                                                const int* __restrict__ dst,
                                                int* __restrict__ rowpos,
                                                unsigned short* __restrict__ csr2,
                                                int E, int N, int rng, int chunk) {
    int b = blockIdx.x;
    int p = b & (NP - 1);
    int lo = p * rng;
    int hi = min(lo + rng, N);
    int base = (b >> 3) * chunk;
    int end = min(base + chunk, E);
    for (int e = base + threadIdx.x; e < end; e += 256) {
        int d = dst[e];
        if (d >= lo && d < hi) {
            int pos = atomicAdd(&rowpos[d], 1);
            if (pos < (d << 6) + MSLOT)  // overflow guard (statistically never)
                __builtin_nontemporal_store((unsigned short)src[e], &csr2[pos]);
        }
    }
}

// ---------------- h' = dinv * (x @ W) via MFMA, stored bf16 (deg from rowpos cursor) ----------------
__global__ __launch_bounds__(256) void gemm_mfma(const float* __restrict__ x,
                                                 const unsigned short* __restrict__ wf,
                                                 const int* __restrict__ rowpos,
                                                 unsigned short* __restrict__ hb, int N) {
    int w = threadIdx.x >> 6;
    int lane = threadIdx.x & 63;
    int rowbase = blockIdx.x * 64 + w * 16;

    bf16x8 bfrag[4][2];
#pragma unroll
    for (int c = 0; c < 4; ++c)
#pragma unroll
        for (int s = 0; s < 2; ++s) {
            u16x8 u = *reinterpret_cast<const u16x8*>(wf + ((c * 2 + s) * 64 + lane) * 8);
            bfrag[c][s] = __builtin_bit_cast(bf16x8, u);
        }

    int ar = rowbase + (lane & 15);
    int k0 = (lane >> 4) * 8;
    bf16x8 afrag[2];
#pragma unroll
    for (int s = 0; s < 2; ++s) {
        u16x8 u = {0, 0, 0, 0, 0, 0, 0, 0};
        if (ar < N) {
            const float* xp = x + (size_t)ar * 64 + 32 * s + k0;
#pragma unroll
            for (int j = 0; j < 8; ++j) u[j] = f2bf(xp[j]);
        }
        afrag[s] = __builtin_bit_cast(bf16x8, u);
    }

    f32x4 acc[4];
#pragma unroll
    for (int c = 0; c < 4; ++c) acc[c] = (f32x4){0.f, 0.f, 0.f, 0.f};
#pragma unroll
    for (int s = 0; s < 2; ++s)
#pragma unroll
        for (int c = 0; c < 4; ++c)
            acc[c] = __builtin_amdgcn_mfma_f32_16x16x32_bf16(afrag[s], bfrag[c][s], acc[c], 0, 0, 0);

    int r0 = rowbase + (lane >> 4) * 4;
    int col = lane & 15;
#pragma unroll
    for (int j = 0; j < 4; ++j) {
        int node = r0 + j;
        if (node < N) {
            int deg = rowpos[node] - (node << 6);
            float dd = rsqrtf(1.0f + (float)deg);
#pragma unroll
            for (int c = 0; c < 4; ++c)
                hb[(size_t)node * 64 + 16 * c + col] = f2bf(acc[c][j] * dd);
        }
    }
}

// ---------------- gather conv: 4 nodes/wave, 16 lanes x uint2; deg from cursor ----------------
__global__ __launch_bounds__(256) void gather_conv(const int* __restrict__ rowpos,
                                                   const unsigned short* __restrict__ csr2,
                                                   const uint2* __restrict__ hb2,
                                                   const float* __restrict__ bia,
                                                   float* __restrict__ out, int N) {
    int nd = blockIdx.x * 16 + (threadIdx.x >> 4);
    if (nd >= N) return;
    int l = threadIdx.x & 15;  // covers cols 4l..4l+3 (8 B)
    int degf = rowpos[nd] - (nd << 6);
    int deg = min(degf, MSLOT);
    float dd = rsqrtf(1.0f + (float)degf);

    uint2 hv = hb2[(size_t)nd * 16 + l];  // self loop (prescaled)
    float a0 = bflo(hv.x), a1 = bfhi(hv.x), a2 = bflo(hv.y), a3 = bfhi(hv.y);
    int s0 = nd << 6;
    int s1 = s0 + deg;
    int j = s0;
    for (; j + 4 <= s1; j += 4) {
        // 4 indices in one 8B load (slot base 128B-aligned, j stays 4-slot aligned)
        unsigned long long iq = *reinterpret_cast<const unsigned long long*>(csr2 + j);
        int i0 = (int)(iq & 0xffff), i1 = (int)((iq >> 16) & 0xffff);
        int i2 = (int)((iq >> 32) & 0xffff), i3 = (int)(iq >> 48);
        uint2 v0 = hb2[(size_t)i0 * 16 + l];
        uint2 v1 = hb2[(size_t)i1 * 16 + l];
        uint2 v2 = hb2[(size_t)i2 * 16 + l];
        uint2 v3 = hb2[(size_t)i3 * 16 + l];
        a0 += bflo(v0.x) + bflo(v1.x) + bflo(v2.x) + bflo(v3.x);
        a1 += bfhi(v0.x) + bfhi(v1.x) + bfhi(v2.x) + bfhi(v3.x);
        a2 += bflo(v0.y) + bflo(v1.y) + bflo(v2.y) + bflo(v3.y);
        a3 += bfhi(v0.y) + bfhi(v1.y) + bfhi(v2.y) + bfhi(v3.y);
    }
    for (; j < s1; ++j) {
        uint2 v = hb2[(size_t)csr2[j] * 16 + l];
        a0 += bflo(v.x);
        a1 += bfhi(v.x);
        a2 += bflo(v.y);
        a3 += bfhi(v.y);
    }
    float4 bb = *reinterpret_cast<const float4*>(bia + 4 * l);
    float4 r;
    r.x = bb.x + dd * a0;
    r.y = bb.y + dd * a1;
    r.z = bb.z + dd * a2;
    r.w = bb.w + dd * a3;
    *reinterpret_cast<float4*>(out + (size_t)nd * 64 + 4 * l) = r;
}

// ---------------- chunk-parallel per-graph sum / sumsq / count ----------------
__global__ __launch_bounds__(256) void stats_partial(const float* __restrict__ out,
                                                     const int* __restrict__ batch,
                                                     float* __restrict__ macc,
                                                     float* __restrict__ vacc,
                                                     int* __restrict__ cntacc, int N) {
    int c0 = blockIdx.x * CH;
    int c1 = min(c0 + CH, N);
    if (c0 >= N) return;
    int t = threadIdx.x, col = t & 63, rg = t >> 6;
    __shared__ int bsh[CH];
    __shared__ float red[4][64], red2[4][64];
    for (int i = t; i < c1 - c0; i += 256) bsh[i] = batch[c0 + i];
    __syncthreads();
    int s = c0;
    while (s < c1) {
        int g = bsh[s - c0];
        int e = s + 1;
        while (e < c1 && bsh[e - c0] == g) ++e;
        float sum = 0.f, sq = 0.f;
        for (int r = s + rg; r < e; r += 4) {
            float v = out[(size_t)r * 64 + col];
            sum += v;
            sq += v * v;
        }
        red[rg][col] = sum;
        red2[rg][col] = sq;
        __syncthreads();
        if (t < 64) {
            atomicAdd(&macc[g * 64 + t], red[0][t] + red[1][t] + red[2][t] + red[3][t]);
            atomicAdd(&vacc[g * 64 + t], red2[0][t] + red2[1][t] + red2[2][t] + red2[3][t]);
        }
        if (t == 0) atomicAdd(&cntacc[g], e - s);
        __syncthreads();
        s = e;
    }
}

// ---------------- final: finalize + normalize + affine + relu, float4 ----------------
__global__ void gn_final(float* __restrict__ out, const int* __restrict__ batch,
                         const float* __restrict__ ms, const float* __restrict__ macc,
                         const float* __restrict__ vacc, const int* __restrict__ cntacc,
                         const float* __restrict__ gw, const float* __restrict__ gb,
                         int total4) {
    int idx = blockIdx.x * 256 + threadIdx.x;
    if (idx >= total4) return;
    int i = idx >> 4, q = idx & 15;
    int g = batch[i];
    float inv = 1.f / (float)max(cntacc[g], 1);
    float4 mv = *reinterpret_cast<const float4*>(macc + g * 64 + 4 * q);
    float4 vv = *reinterpret_cast<const float4*>(vacc + g * 64 + 4 * q);
    float4 msf = *reinterpret_cast<const float4*>(ms + 4 * q);
    float4 gwv = *reinterpret_cast<const float4*>(gw + 4 * q);
    float4 gbv = *reinterpret_cast<const float4*>(gb + 4 * q);
    float4 o = *reinterpret_cast<const float4*>(out + (size_t)i * 64 + 4 * q);
    float m, var, y;
    float4 res;
    m = mv.x * inv; var = vv.x * inv - m * m * msf.x * (2.f - msf.x);
    y = (o.x - msf.x * m) * rsqrtf(var + EPS); res.x = fmaxf(gwv.x * y + gbv.x, 0.f);
    m = mv.y * inv; var = vv.y * inv - m * m * msf.y * (2.f - msf.y);
    y = (o.y - msf.y * m) * rsqrtf(var + EPS); res.y = fmaxf(gwv.y * y + gbv.y, 0.f);
    m = mv.z * inv; var = vv.z * inv - m * m * msf.z * (2.f - msf.z);
    y = (o.z - msf.z * m) * rsqrtf(var + EPS); res.z = fmaxf(gwv.z * y + gbv.z, 0.f);
    m = mv.w * inv; var = vv.w * inv - m * m * msf.w * (2.f - msf.w);
    y = (o.w - msf.w * m) * rsqrtf(var + EPS); res.w = fmaxf(gwv.w * y + gbv.w, 0.f);
    *reinterpret_cast<float4*>(out + (size_t)i * 64 + 4 * q) = res;
}

extern "C" void kernel_launch(void* const* d_in, const int* in_sizes, int n_in,
                              void* d_out, int out_size, void* d_ws, size_t ws_size,
                              hipStream_t stream) {
    const float* x  = (const float*)d_in[0];
    const float* W  = (const float*)d_in[1];
    const float* b  = (const float*)d_in[2];
    const float* gw = (const float*)d_in[3];
    const float* gb = (const float*)d_in[4];
    const float* ms = (const float*)d_in[5];
    const int*   edge  = (const int*)d_in[6];
    const int*   batch = (const int*)d_in[7];

    int N = in_sizes[0] / 64;
    int E = in_sizes[6] / 2;
    const int* src = edge;
    const int* dst = edge + E;

    float* out = (float*)d_out;

    // workspace layout (contiguous zero region: macc | vacc | cntacc); 8B-aligned
    unsigned short* hb = (unsigned short*)d_ws;          // N*64 bf16 (prescaled)
    int*   rowpos    = (int*)(hb + (size_t)N * 64);      // N int (write cursors)
    float* macc      = (float*)(rowpos + N);             // 64*64
    float* vacc      = macc + 64 * 64;                   // 64*64
    int*   cntacc    = (int*)(vacc + 64 * 64);           // 64 (+pad to 80)
    unsigned short* csr2 = (unsigned short*)(cntacc + 80);  // N*64 ushort (padded slots)
    unsigned short* wf   = csr2 + (size_t)N * MSLOT;     // 4096 bf16 W-fragments

    int chunk = (E + 255) / 256;              // per-block edge chunk (256 blocks/partition)
    int rng = (N + NP - 1) / NP;              // nodes per partition
    int zcount = 2 * 64 * 64 + 80;            // macc + vacc + cntacc(+pad)
    int setup_n = max(N, zcount);

    setup<<<(setup_n + 255) / 256, 256, 0, stream>>>(W, wf, rowpos, N, (int*)macc, zcount);
    fill_xcd<<<2048, 256, 0, stream>>>(src, dst, rowpos, csr2, E, N, rng, chunk);
    gemm_mfma<<<(N + 63) / 64, 256, 0, stream>>>(x, wf, rowpos, hb, N);
    gather_conv<<<(N + 15) / 16, 256, 0, stream>>>(rowpos, csr2, (const uint2*)hb, b, out, N);
    stats_partial<<<(N + CH - 1) / CH, 256, 0, stream>>>(out, batch, macc, vacc, cntacc, N);
    gn_final<<<(N * 16 + 255) / 256, 256, 0, stream>>>(out, batch, ms, macc, vacc, cntacc,
                                                       gw, gb, N * 16);
}

// Round 15
// 102.169 us; speedup vs baseline: 1.5849x; 1.0081x over previous
//
#include <hip/hip_runtime.h>
#include <stdint.h>

#define EPS 1e-5f
#define NG 64
#define NP 8      // dst-range partitions (== XCD count; partition p = blockIdx & 7)
#define MSLOT 64  // padded CSR slot per node (deg ~ Poisson(16); P(>64) ~ 1e-20)
#define CH 128    // rows per stats chunk

typedef float f32x4 __attribute__((ext_vector_type(4)));
typedef __bf16 bf16x8 __attribute__((ext_vector_type(8)));
typedef unsigned short u16x8 __attribute__((ext_vector_type(8)));

__device__ __forceinline__ unsigned short f2bf(float f) {
    union { float f; uint32_t u; } v; v.f = f;
    uint32_t r = v.u + 0x7fff + ((v.u >> 16) & 1);  // round-to-nearest-even
    return (unsigned short)(r >> 16);
}
__device__ __forceinline__ float bflo(uint32_t u) {
    union { uint32_t u; float f; } v; v.u = u << 16; return v.f;
}
__device__ __forceinline__ float bfhi(uint32_t u) {
    union { uint32_t u; float f; } v; v.u = u & 0xffff0000u; return v.f;
}

// ---------------- setup: rowpos[i] = i*64, zero accumulators, build W fragments ----------------
__global__ __launch_bounds__(256) void setup(const float* __restrict__ W,
                                             unsigned short* __restrict__ wf,
                                             int* __restrict__ rowpos, int N,
                                             int* __restrict__ zbase, int zcount) {
    int i = blockIdx.x * 256 + threadIdx.x;
    if (i < N) rowpos[i] = i << 6;
    if (i < zcount) zbase[i] = 0;
    if (blockIdx.x == 0) {
        for (int k = threadIdx.x; k < 512; k += 256) {
            int lane = k & 63;
            int c = k >> 7;
            int s = (k >> 6) & 1;
            int col = 16 * c + (lane & 15);
            int k0 = 32 * s + (lane >> 4) * 8;
#pragma unroll
            for (int j = 0; j < 8; ++j)
                wf[k * 8 + j] = f2bf(W[(k0 + j) * 64 + col]);
        }
    }
}

// ---------------- fill: dst-range partitioned -> ALL atomics & stores XCD-local ----------------
__global__ __launch_bounds__(256) void fill_xcd(const int* __restrict__ src,
                                                const int* __restrict__ dst,
                                                int* __restrict__ rowpos,
                                                unsigned short* __restrict__ csr2,
                                                int E, int N, int rng, int chunk) {
    int b = blockIdx.x;
    int p = b & (NP - 1);
    int lo = p * rng;
    int hi = min(lo + rng, N);
    int base = (b >> 3) * chunk;
    int end = min(base + chunk, E);
    for (int e = base + threadIdx.x; e < end; e += 256) {
        int d = dst[e];
        if (d >= lo && d < hi) {
            int pos = atomicAdd(&rowpos[d], 1);
            if (pos < (d << 6) + MSLOT)  // overflow guard (statistically never)
                __builtin_nontemporal_store((unsigned short)src[e], &csr2[pos]);
        }
    }
}

// ---------------- h' = dinv * (x @ W) via MFMA, stored bf16 (deg from rowpos cursor) ----------------
__global__ __launch_bounds__(256) void gemm_mfma(const float* __restrict__ x,
                                                 const unsigned short* __restrict__ wf,
                                                 const int* __restrict__ rowpos,
                                                 unsigned short* __restrict__ hb, int N) {
    int w = threadIdx.x >> 6;
    int lane = threadIdx.x & 63;
    int rowbase = blockIdx.x * 64 + w * 16;

    bf16x8 bfrag[4][2];
#pragma unroll
    for (int c = 0; c < 4; ++c)
#pragma unroll
        for (int s = 0; s < 2; ++s) {
            u16x8 u = *reinterpret_cast<const u16x8*>(wf + ((c * 2 + s) * 64 + lane) * 8);
            bfrag[c][s] = __builtin_bit_cast(bf16x8, u);
        }

    int ar = rowbase + (lane & 15);
    int k0 = (lane >> 4) * 8;
    bf16x8 afrag[2];
#pragma unroll
    for (int s = 0; s < 2; ++s) {
        u16x8 u = {0, 0, 0, 0, 0, 0, 0, 0};
        if (ar < N) {
            const float* xp = x + (size_t)ar * 64 + 32 * s + k0;
#pragma unroll
            for (int j = 0; j < 8; ++j) u[j] = f2bf(xp[j]);
        }
        afrag[s] = __builtin_bit_cast(bf16x8, u);
    }

    f32x4 acc[4];
#pragma unroll
    for (int c = 0; c < 4; ++c) acc[c] = (f32x4){0.f, 0.f, 0.f, 0.f};
#pragma unroll
    for (int s = 0; s < 2; ++s)
#pragma unroll
        for (int c = 0; c < 4; ++c)
            acc[c] = __builtin_amdgcn_mfma_f32_16x16x32_bf16(afrag[s], bfrag[c][s], acc[c], 0, 0, 0);

    int r0 = rowbase + (lane >> 4) * 4;
    int col = lane & 15;
#pragma unroll
    for (int j = 0; j < 4; ++j) {
        int node = r0 + j;
        if (node < N) {
            int deg = rowpos[node] - (node << 6);
            float dd = rsqrtf(1.0f + (float)deg);
#pragma unroll
            for (int c = 0; c < 4; ++c)
                hb[(size_t)node * 64 + 16 * c + col] = f2bf(acc[c][j] * dd);
        }
    }
}

// ---------------- gather conv: 4 nodes/wave, 16 lanes x uint2; 8-deep unroll ----------------
__global__ __launch_bounds__(256) void gather_conv(const int* __restrict__ rowpos,
                                                   const unsigned short* __restrict__ csr2,
                                                   const uint2* __restrict__ hb2,
                                                   const float* __restrict__ bia,
                                                   float* __restrict__ out, int N) {
    int nd = blockIdx.x * 16 + (threadIdx.x >> 4);
    if (nd >= N) return;
    int l = threadIdx.x & 15;  // covers cols 4l..4l+3 (8 B)
    int degf = rowpos[nd] - (nd << 6);
    int deg = min(degf, MSLOT);
    float dd = rsqrtf(1.0f + (float)degf);

    uint2 hv = hb2[(size_t)nd * 16 + l];  // self loop (prescaled)
    float a0 = bflo(hv.x), a1 = bfhi(hv.x), a2 = bflo(hv.y), a3 = bfhi(hv.y);
    float b0 = 0.f, b1 = 0.f, b2 = 0.f, b3 = 0.f;  // second accumulator set
    int s0 = nd << 6;
    int s1 = s0 + deg;
    int j = s0;
    // 8-deep: one 16B index load -> 8 independent row loads in flight
    for (; j + 8 <= s1; j += 8) {
        uint4 iq = *reinterpret_cast<const uint4*>(csr2 + j);  // 16B aligned (j%8==0, base 128B)
        int i0 = (int)(iq.x & 0xffff), i1 = (int)(iq.x >> 16);
        int i2 = (int)(iq.y & 0xffff), i3 = (int)(iq.y >> 16);
        int i4 = (int)(iq.z & 0xffff), i5 = (int)(iq.z >> 16);
        int i6 = (int)(iq.w & 0xffff), i7 = (int)(iq.w >> 16);
        uint2 v0 = hb2[(size_t)i0 * 16 + l];
        uint2 v1 = hb2[(size_t)i1 * 16 + l];
        uint2 v2 = hb2[(size_t)i2 * 16 + l];
        uint2 v3 = hb2[(size_t)i3 * 16 + l];
        uint2 v4 = hb2[(size_t)i4 * 16 + l];
        uint2 v5 = hb2[(size_t)i5 * 16 + l];
        uint2 v6 = hb2[(size_t)i6 * 16 + l];
        uint2 v7 = hb2[(size_t)i7 * 16 + l];
        a0 += bflo(v0.x) + bflo(v1.x) + bflo(v2.x) + bflo(v3.x);
        a1 += bfhi(v0.x) + bfhi(v1.x) + bfhi(v2.x) + bfhi(v3.x);
        a2 += bflo(v0.y) + bflo(v1.y) + bflo(v2.y) + bflo(v3.y);
        a3 += bfhi(v0.y) + bfhi(v1.y) + bfhi(v2.y) + bfhi(v3.y);
        b0 += bflo(v4.x) + bflo(v5.x) + bflo(v6.x) + bflo(v7.x);
        b1 += bfhi(v4.x) + bfhi(v5.x) + bfhi(v6.x) + bfhi(v7.x);
        b2 += bflo(v4.y) + bflo(v5.y) + bflo(v6.y) + bflo(v7.y);
        b3 += bfhi(v4.y) + bfhi(v5.y) + bfhi(v6.y) + bfhi(v7.y);
    }
    for (; j + 4 <= s1; j += 4) {
        unsigned long long iq = *reinterpret_cast<const unsigned long long*>(csr2 + j);
        int i0 = (int)(iq & 0xffff), i1 = (int)((iq >> 16) & 0xffff);
        int i2 = (int)((iq >> 32) & 0xffff), i3 = (int)(iq >> 48);
        uint2 v0 = hb2[(size_t)i0 * 16 + l];
        uint2 v1 = hb2[(size_t)i1 * 16 + l];
        uint2 v2 = hb2[(size_t)i2 * 16 + l];
        uint2 v3 = hb2[(size_t)i3 * 16 + l];
        a0 += bflo(v0.x) + bflo(v1.x) + bflo(v2.x) + bflo(v3.x);
        a1 += bfhi(v0.x) + bfhi(v1.x) + bfhi(v2.x) + bfhi(v3.x);
        a2 += bflo(v0.y) + bflo(v1.y) + bflo(v2.y) + bflo(v3.y);
        a3 += bfhi(v0.y) + bfhi(v1.y) + bfhi(v2.y) + bfhi(v3.y);
    }
    for (; j < s1; ++j) {
        uint2 v = hb2[(size_t)csr2[j] * 16 + l];
        a0 += bflo(v.x);
        a1 += bfhi(v.x);
        a2 += bflo(v.y);
        a3 += bfhi(v.y);
    }
    a0 += b0; a1 += b1; a2 += b2; a3 += b3;
    float4 bb = *reinterpret_cast<const float4*>(bia + 4 * l);
    float4 r;
    r.x = bb.x + dd * a0;
    r.y = bb.y + dd * a1;
    r.z = bb.z + dd * a2;
    r.w = bb.w + dd * a3;
    *reinterpret_cast<float4*>(out + (size_t)nd * 64 + 4 * l) = r;
}

// ---------------- chunk-parallel per-graph sum / sumsq / count ----------------
__global__ __launch_bounds__(256) void stats_partial(const float* __restrict__ out,
                                                     const int* __restrict__ batch,
                                                     float* __restrict__ macc,
                                                     float* __restrict__ vacc,
                                                     int* __restrict__ cntacc, int N) {
    int c0 = blockIdx.x * CH;
    int c1 = min(c0 + CH, N);
    if (c0 >= N) return;
    int t = threadIdx.x, col = t & 63, rg = t >> 6;
    __shared__ int bsh[CH];
    __shared__ float red[4][64], red2[4][64];
    for (int i = t; i < c1 - c0; i += 256) bsh[i] = batch[c0 + i];
    __syncthreads();
    int s = c0;
    while (s < c1) {
        int g = bsh[s - c0];
        int e = s + 1;
        while (e < c1 && bsh[e - c0] == g) ++e;
        float sum = 0.f, sq = 0.f;
        for (int r = s + rg; r < e; r += 4) {
            float v = out[(size_t)r * 64 + col];
            sum += v;
            sq += v * v;
        }
        red[rg][col] = sum;
        red2[rg][col] = sq;
        __syncthreads();
        if (t < 64) {
            atomicAdd(&macc[g * 64 + t], red[0][t] + red[1][t] + red[2][t] + red[3][t]);
            atomicAdd(&vacc[g * 64 + t], red2[0][t] + red2[1][t] + red2[2][t] + red2[3][t]);
        }
        if (t == 0) atomicAdd(&cntacc[g], e - s);
        __syncthreads();
        s = e;
    }
}

// ---------------- final: finalize + normalize + affine + relu, float4 ----------------
__global__ void gn_final(float* __restrict__ out, const int* __restrict__ batch,
                         const float* __restrict__ ms, const float* __restrict__ macc,
                         const float* __restrict__ vacc, const int* __restrict__ cntacc,
                         const float* __restrict__ gw, const float* __restrict__ gb,
                         int total4) {
    int idx = blockIdx.x * 256 + threadIdx.x;
    if (idx >= total4) return;
    int i = idx >> 4, q = idx & 15;
    int g = batch[i];
    float inv = 1.f / (float)max(cntacc[g], 1);
    float4 mv = *reinterpret_cast<const float4*>(macc + g * 64 + 4 * q);
    float4 vv = *reinterpret_cast<const float4*>(vacc + g * 64 + 4 * q);
    float4 msf = *reinterpret_cast<const float4*>(ms + 4 * q);
    float4 gwv = *reinterpret_cast<const float4*>(gw + 4 * q);
    float4 gbv = *reinterpret_cast<const float4*>(gb + 4 * q);
    float4 o = *reinterpret_cast<const float4*>(out + (size_t)i * 64 + 4 * q);
    float m, var, y;
    float4 res;
    m = mv.x * inv; var = vv.x * inv - m * m * msf.x * (2.f - msf.x);
    y = (o.x - msf.x * m) * rsqrtf(var + EPS); res.x = fmaxf(gwv.x * y + gbv.x, 0.f);
    m = mv.y * inv; var = vv.y * inv - m * m * msf.y * (2.f - msf.y);
    y = (o.y - msf.y * m) * rsqrtf(var + EPS); res.y = fmaxf(gwv.y * y + gbv.y, 0.f);
    m = mv.z * inv; var = vv.z * inv - m * m * msf.z * (2.f - msf.z);
    y = (o.z - msf.z * m) * rsqrtf(var + EPS); res.z = fmaxf(gwv.z * y + gbv.z, 0.f);
    m = mv.w * inv; var = vv.w * inv - m * m * msf.w * (2.f - msf.w);
    y = (o.w - msf.w * m) * rsqrtf(var + EPS); res.w = fmaxf(gwv.w * y + gbv.w, 0.f);
    *reinterpret_cast<float4*>(out + (size_t)i * 64 + 4 * q) = res;
}

extern "C" void kernel_launch(void* const* d_in, const int* in_sizes, int n_in,
                              void* d_out, int out_size, void* d_ws, size_t ws_size,
                              hipStream_t stream) {
    const float* x  = (const float*)d_in[0];
    const float* W  = (const float*)d_in[1];
    const float* b  = (const float*)d_in[2];
    const float* gw = (const float*)d_in[3];
    const float* gb = (const float*)d_in[4];
    const float* ms = (const float*)d_in[5];
    const int*   edge  = (const int*)d_in[6];
    const int*   batch = (const int*)d_in[7];

    int N = in_sizes[0] / 64;
    int E = in_sizes[6] / 2;
    const int* src = edge;
    const int* dst = edge + E;

    float* out = (float*)d_out;

    // workspace layout (contiguous zero region: macc | vacc | cntacc); 16B-aligned throughout
    unsigned short* hb = (unsigned short*)d_ws;          // N*64 bf16 (prescaled)
    int*   rowpos    = (int*)(hb + (size_t)N * 64);      // N int (write cursors)
    float* macc      = (float*)(rowpos + N);             // 64*64
    float* vacc      = macc + 64 * 64;                   // 64*64
    int*   cntacc    = (int*)(vacc + 64 * 64);           // 64 (+pad to 80)
    unsigned short* csr2 = (unsigned short*)(cntacc + 80);  // N*64 ushort (padded slots)
    unsigned short* wf   = csr2 + (size_t)N * MSLOT;     // 4096 bf16 W-fragments

    int chunk = (E + 255) / 256;              // per-block edge chunk (256 blocks/partition)
    int rng = (N + NP - 1) / NP;              // nodes per partition
    int zcount = 2 * 64 * 64 + 80;            // macc + vacc + cntacc(+pad)
    int setup_n = max(N, zcount);

    setup<<<(setup_n + 255) / 256, 256, 0, stream>>>(W, wf, rowpos, N, (int*)macc, zcount);
    fill_xcd<<<2048, 256, 0, stream>>>(src, dst, rowpos, csr2, E, N, rng, chunk);
    gemm_mfma<<<(N + 63) / 64, 256, 0, stream>>>(x, wf, rowpos, hb, N);
    gather_conv<<<(N + 15) / 16, 256, 0, stream>>>(rowpos, csr2, (const uint2*)hb, b, out, N);
    stats_partial<<<(N + CH - 1) / CH, 256, 0, stream>>>(out, batch, macc, vacc, cntacc, N);
    gn_final<<<(N * 16 + 255) / 256, 256, 0, stream>>>(out, batch, ms, macc, vacc, cntacc,
                                                       gw, gb, N * 16);
}